// Round 5
// baseline (3494.433 us; speedup 1.0000x reference)
//
#include <hip/hip_runtime.h>
#include <hip/hip_bf16.h>
#include <hip/hip_cooperative_groups.h>

namespace cg = cooperative_groups;

#define Bq 16
#define Tq 256
#define Vq 18000
#define NSq 30
#define Lq 10
#define Gq 3
#define Hq 400
#define Nq (NSq * Bq)      // 480
#define H3q (3 * Hq)       // 1200
#define NKT 25             // K tiles (400/16)
#define NGV 564            // embp col groups (32 cols each; 18048 padded)
#define NGW 38             // weight col groups (1216 padded)
#define NGH 15             // row groups (480 rows)
#define NVU 564            // vocab units per step (32 cols each)
#define NPB2 576           // partial stride (564 used)
#define NGT 152            // gh units (38 ct x 4 gsets)
#define NGI 380            // gi units (38 ct x 10 steps)
#define GRID 480

typedef __bf16 bf16;
typedef __bf16 bf16x4 __attribute__((ext_vector_type(4)));
typedef __bf16 bf16x8 __attribute__((ext_vector_type(8)));
typedef float floatx16 __attribute__((ext_vector_type(16)));

struct MegaP {
    const float* ehid; const float* enc; const float* emb;
    const float* w_ih; const float* w_hh; const float* b_ih; const float* b_hh;
    const float* w_ratio; const float* b_ratio;
    const float* w_gate; const float* b_gate; const float* slot_emb;
    const int* lens; const int* story; const int* tgt;
    const int* dom; const int* slo;
    float* out; float* out_gates;
    bf16* xbp; bf16* xlin; bf16* hbp;
    float* h; float* gi_all; float* gh;
    float* prob0; float* prob1; float* swp0; float* swp1;
    float* partial; bf16* eLb;
    bf16* embp; bf16* wihp; bf16* whhp; bf16* encb;
};

// ---------------------------------------------------------------------------
// Pack one MFMA fragment (8 bf16) from a row-major f32 [nrows][400] matrix.
// frag i = ((g*25+kt)*64+lane): src(row=g*32+(lane&31), k=kt*16+(lane>>5)*8+j)
// ---------------------------------------------------------------------------
__device__ __forceinline__ void packf_one(const float* __restrict__ src,
    bf16* __restrict__ dst, const int i, const int nrows)
{
    const int lane = i & 63;
    const int kt = (i >> 6) % NKT;
    const int g = i / (NKT * 64);
    int row = g * 32 + (lane & 31);
    if (row >= nrows) row = nrows - 1;
    const int k0 = kt * 16 + (lane >> 5) * 8;
    const float* s = src + (size_t)row * Hq + k0;
    const float4 a = *(const float4*)s;
    const float4 c = *(const float4*)(s + 4);
    bf16x8 o;
    o[0] = (bf16)a.x; o[1] = (bf16)a.y; o[2] = (bf16)a.z; o[3] = (bf16)a.w;
    o[4] = (bf16)c.x; o[5] = (bf16)c.y; o[6] = (bf16)c.z; o[7] = (bf16)c.w;
    *(bf16x8*)(dst + (size_t)i * 8) = o;
}

// ---------------------------------------------------------------------------
// Phase 0: all one-time packs/conversions (independent of each other).
// ---------------------------------------------------------------------------
__device__ void phase0_body(const MegaP& p, const int gtid, const int GT)
{
    for (int i = gtid; i < NGV * NKT * 64; i += GT)
        packf_one(p.emb, p.embp, i, Vq);
    for (int i = gtid; i < NGW * NKT * 64; i += GT) {
        packf_one(p.w_ih, p.wihp, i, H3q);
        packf_one(p.w_hh, p.whhp, i, H3q);
    }
    for (int i = gtid; i < (Bq * Tq * Hq) / 4; i += GT) {
        const float4 v = ((const float4*)p.enc)[i];
        bf16x4 o;
        o[0] = (bf16)v.x; o[1] = (bf16)v.y; o[2] = (bf16)v.z; o[3] = (bf16)v.w;
        ((bf16x4*)p.encb)[i] = o;
    }
    for (int i = gtid; i < Lq * NGH * NKT * 64; i += GT) {
        const int lane = i & 63;
        const int kt = (i >> 6) % NKT;
        const int gg = i / (NKT * 64);
        const int g = gg % NGH;
        const int s = gg / NGH;
        const int n = g * 32 + (lane & 31);
        const int slot = n >> 4, b = n & (Bq - 1);
        const int k0 = kt * 16 + (lane >> 5) * 8;
        float v[8];
        if (s == 0) {
            const float* p1 = p.slot_emb + (size_t)p.dom[slot] * Hq + k0;
            const float* p2 = p.slot_emb + (size_t)p.slo[slot] * Hq + k0;
            #pragma unroll
            for (int j = 0; j < 8; ++j) v[j] = p1[j] + p2[j];
        } else {
            const int tv = p.tgt[(b * NSq + slot) * Lq + (s - 1)];
            const float* q = p.emb + (size_t)tv * Hq + k0;
            #pragma unroll
            for (int j = 0; j < 8; ++j) v[j] = q[j];
        }
        bf16x8 o;
        #pragma unroll
        for (int j = 0; j < 8; ++j) o[j] = (bf16)v[j];
        *(bf16x8*)(p.xbp + (size_t)i * 8) = o;
        *(bf16x8*)(p.xlin + ((size_t)s * Nq + n) * Hq + k0) = o;
    }
    for (int i = gtid; i < NGH * NKT * 64; i += GT) {
        const int lane = i & 63;
        const int kt = (i >> 6) % NKT;
        const int g = i / (NKT * 64);
        const int n = g * 32 + (lane & 31);
        const int b = n & (Bq - 1);
        const int k0 = kt * 16 + (lane >> 5) * 8;
        const float* s = p.ehid + (size_t)b * Hq + k0;
        bf16x8 o;
        #pragma unroll
        for (int j = 0; j < 8; ++j) {
            const float v = s[j];
            p.h[(size_t)n * Hq + k0 + j] = v;
            o[j] = (bf16)v;
        }
        *(bf16x8*)(p.hbp + (size_t)i * 8) = o;
    }
}

// ---------------------------------------------------------------------------
// gh unit v in [0,152): gh = h_prev @ W_hh^T, one wave per (ct, g).
// ---------------------------------------------------------------------------
__device__ __forceinline__ void gh_unit(const MegaP& p, const int v,
                                        const int wave, const int lane)
{
    const int ct = v % NGW;
    const int g = (v / NGW) * 4 + wave;
    if (g >= NGH) return;
    floatx16 acc;
    #pragma unroll
    for (int r = 0; r < 16; ++r) acc[r] = 0.f;
    for (int kt = 0; kt < NKT; ++kt) {
        const bf16x8 a = *(const bf16x8*)(p.hbp + ((size_t)(g * NKT + kt) * 64 + lane) * 8);
        const bf16x8 w = *(const bf16x8*)(p.whhp + ((size_t)(ct * NKT + kt) * 64 + lane) * 8);
        acc = __builtin_amdgcn_mfma_f32_32x32x16_bf16(a, w, acc, 0, 0, 0);
    }
    const int j = ct * 32 + (lane & 31);
    if (j >= H3q) return;
    const int rbase = g * 32 + 4 * (lane >> 5);
    #pragma unroll
    for (int r = 0; r < 16; ++r) {
        const int rr = rbase + (r & 3) + 8 * (r >> 2);
        p.gh[(size_t)rr * H3q + j] = acc[r];
    }
}

// ---------------------------------------------------------------------------
// gi unit u in [0,380): gi_all[s] = x_s @ W_ih^T, block-wide (4 waves x 4 g).
// ---------------------------------------------------------------------------
__device__ __forceinline__ void gi_unit(const MegaP& p, const int u,
                                        const int wave, const int lane)
{
    const int ct = u % NGW;
    const int s = u / NGW;
    floatx16 acc[4];
    #pragma unroll
    for (int i = 0; i < 4; ++i)
        #pragma unroll
        for (int r = 0; r < 16; ++r) acc[i][r] = 0.f;
    for (int kt = 0; kt < NKT; ++kt) {
        const bf16x8 w = *(const bf16x8*)(p.wihp + ((size_t)(ct * NKT + kt) * 64 + lane) * 8);
        #pragma unroll
        for (int i = 0; i < 4; ++i) {
            const int g = wave + 4 * i;
            if (g < NGH) {
                const bf16x8 a = *(const bf16x8*)(p.xbp +
                    ((size_t)((s * NGH + g) * NKT + kt) * 64 + lane) * 8);
                acc[i] = __builtin_amdgcn_mfma_f32_32x32x16_bf16(a, w, acc[i], 0, 0, 0);
            }
        }
    }
    const int j = ct * 32 + (lane & 31);
    if (j >= H3q) return;
    #pragma unroll
    for (int i = 0; i < 4; ++i) {
        const int g = wave + 4 * i;
        if (g < NGH) {
            const int rbase = g * 32 + 4 * (lane >> 5);
            #pragma unroll
            for (int r = 0; r < 16; ++r) {
                const int rr = rbase + (r & 3) + 8 * (r >> 2);
                p.gi_all[((size_t)(s * Nq + rr)) * H3q + j] = acc[i][r];
            }
        }
    }
}

// ---------------------------------------------------------------------------
// vocab unit u in [0,564): 32 cols of logits -> exp -> bf16 eLb + partial sum.
// ---------------------------------------------------------------------------
__device__ __forceinline__ void vocab_unit(const MegaP& p, const int u,
                                           const int wave, const int lane)
{
    floatx16 acc[4];
    #pragma unroll
    for (int i = 0; i < 4; ++i)
        #pragma unroll
        for (int r = 0; r < 16; ++r) acc[i][r] = 0.f;
    for (int kt = 0; kt < NKT; ++kt) {
        const bf16x8 w = *(const bf16x8*)(p.embp + ((size_t)(u * NKT + kt) * 64 + lane) * 8);
        #pragma unroll
        for (int i = 0; i < 4; ++i) {
            const int g = wave + 4 * i;
            if (g < NGH) {
                const bf16x8 a = *(const bf16x8*)(p.hbp +
                    ((size_t)(g * NKT + kt) * 64 + lane) * 8);
                acc[i] = __builtin_amdgcn_mfma_f32_32x32x16_bf16(a, w, acc[i], 0, 0, 0);
            }
        }
    }
    const int mcol = lane & 31, half = lane >> 5;
    const int j0 = u * 32 + mcol;
    #pragma unroll
    for (int i = 0; i < 4; ++i) {
        const int g = wave + 4 * i;      // wave-uniform; shfl below is safe
        if (g >= NGH) continue;
        const int rbase = g * 32 + 4 * half;
        #pragma unroll
        for (int r = 0; r < 16; ++r) {
            const int rr = rbase + (r & 3) + 8 * (r >> 2);
            const float e0 = (j0 < Vq) ? __expf(acc[i][r]) : 0.f;
            if (j0 < Vq) p.eLb[(size_t)rr * Vq + j0] = (bf16)e0;
            float v = e0;
            v += __shfl_xor(v, 16, 64);
            v += __shfl_xor(v, 8, 64);
            v += __shfl_xor(v, 4, 64);
            v += __shfl_xor(v, 2, 64);
            v += __shfl_xor(v, 1, 64);
            if (mcol == 0) p.partial[(size_t)rr * NPB2 + u] = v;
        }
    }
}

// ---------------------------------------------------------------------------
// attn row n at step: GRU nonlin + attention + context + switch (+gates@0).
// (round-3 proven body; per-thread scores over encb rows)
// ---------------------------------------------------------------------------
__device__ void attn_row(const MegaP& p, const int n, const int step,
    float* __restrict__ prob_a, float* __restrict__ swp_a,
    float* s_h, float* s_c, float* s_p, float* s_red)
{
    const int b = n & (Bq - 1);
    const int tid = threadIdx.x;

    const float* gin = p.gi_all + ((size_t)step * Nq + n) * H3q;
    const float* ghn = p.gh + (size_t)n * H3q;
    for (int k = tid; k < Hq; k += 256) {
        float ir = gin[k]          + p.b_ih[k];
        float hr = ghn[k]          + p.b_hh[k];
        float iz = gin[Hq + k]     + p.b_ih[Hq + k];
        float hz = ghn[Hq + k]     + p.b_hh[Hq + k];
        float in_ = gin[2*Hq + k]  + p.b_ih[2*Hq + k];
        float hn_ = ghn[2*Hq + k]  + p.b_hh[2*Hq + k];
        float r = 1.f / (1.f + __expf(-(ir + hr)));
        float z = 1.f / (1.f + __expf(-(iz + hz)));
        float nn = tanhf(in_ + r * hn_);
        float hp = p.h[(size_t)n * Hq + k];
        float hv = (1.f - z) * nn + z * hp;
        s_h[k] = hv;
        p.h[(size_t)n * Hq + k] = hv;
        p.hbp[((size_t)(((n >> 5) * NKT + (k >> 4)) * 64
                        + ((k >> 3) & 1) * 32 + (n & 31))) * 8 + (k & 7)] = (bf16)hv;
    }
    __syncthreads();

    // scores: thread t over T=256 (independent, ILP-friendly)
    const int t = tid;
    const bf16* erow = p.encb + (size_t)(b * Tq + t) * Hq;
    float sc = 0.f;
    #pragma unroll 5
    for (int kc = 0; kc < Hq / 8; ++kc) {
        const bf16x8 e = *(const bf16x8*)(erow + kc * 8);
        #pragma unroll
        for (int j = 0; j < 8; ++j) sc += s_h[kc * 8 + j] * (float)e[j];
    }
    const int len = p.lens[b];
    float score = (t < len) ? sc : -1e9f;

    float mx = score;
    for (int off = 32; off > 0; off >>= 1) mx = fmaxf(mx, __shfl_xor(mx, off, 64));
    if ((tid & 63) == 0) s_red[tid >> 6] = mx;
    __syncthreads();
    mx = fmaxf(fmaxf(s_red[0], s_red[1]), fmaxf(s_red[2], s_red[3]));
    float ev = __expf(score - mx);
    float sm = ev;
    for (int off = 32; off > 0; off >>= 1) sm += __shfl_xor(sm, off, 64);
    __syncthreads();
    if ((tid & 63) == 0) s_red[tid >> 6] = sm;
    __syncthreads();
    sm = s_red[0] + s_red[1] + s_red[2] + s_red[3];
    const float pv = ev / sm;
    s_p[t] = pv;
    prob_a[(size_t)n * Tq + t] = pv;
    __syncthreads();

    // context[k] = sum_t p[t] * enc[b][t][k]
    for (int k = tid; k < Hq; k += 256) {
        float c = 0.f;
        const bf16* ecol = p.encb + (size_t)b * Tq * Hq + k;
        for (int tt = 0; tt < Tq; ++tt) c += s_p[tt] * (float)ecol[(size_t)tt * Hq];
        s_c[k] = c;
    }
    __syncthreads();

    const bf16* xr = p.xlin + ((size_t)step * Nq + n) * Hq;
    float part2 = 0.f;
    for (int k = tid; k < Hq; k += 256) {
        part2 += p.w_ratio[k]        * s_h[k]
               + p.w_ratio[Hq + k]   * s_c[k]
               + p.w_ratio[2*Hq + k] * (float)xr[k];
    }
    for (int off = 32; off > 0; off >>= 1) part2 += __shfl_xor(part2, off, 64);
    __syncthreads();
    if ((tid & 63) == 0) s_red[tid >> 6] = part2;
    __syncthreads();
    if (tid == 0) {
        const float tot = s_red[0] + s_red[1] + s_red[2] + s_red[3] + p.b_ratio[0];
        swp_a[n] = 1.f / (1.f + __expf(-tot));
    }

    if (step == 0) {
        for (int gg = 0; gg < Gq; ++gg) {
            float pg = 0.f;
            for (int k = tid; k < Hq; k += 256)
                pg += p.w_gate[gg * Hq + k] * s_c[k];
            for (int off = 32; off > 0; off >>= 1) pg += __shfl_xor(pg, off, 64);
            __syncthreads();
            if ((tid & 63) == 0) s_red[tid >> 6] = pg;
            __syncthreads();
            if (tid == 0)
                p.out_gates[n * Gq + gg] =
                    s_red[0] + s_red[1] + s_red[2] + s_red[3] + p.b_gate[gg];
        }
    }
}

// ---------------------------------------------------------------------------
// final row n at step: rowsum from partials; scale eLb into LDS; LDS-atomic
// pointer scatter; coalesced f32 store. (round-3 proven pattern, 1 chunk)
// ---------------------------------------------------------------------------
__device__ void final_row(const MegaP& p, const int n, const int step,
    const float* __restrict__ prob_f, const float* __restrict__ swp_f,
    float* s_chunk, float* s_red)
{
    const int tid = threadIdx.x;
    const int b = n & (Bq - 1);

    float ps = 0.f;
    for (int i = tid; i < NVU; i += 256) ps += p.partial[(size_t)n * NPB2 + i];
    #pragma unroll
    for (int off = 32; off > 0; off >>= 1) ps += __shfl_xor(ps, off, 64);
    if ((tid & 63) == 0) s_red[tid >> 6] = ps;
    __syncthreads();
    const float rs = s_red[0] + s_red[1] + s_red[2] + s_red[3];
    const float swv = swp_f[n];
    const float scale = swv / rs;

    const bf16* er = p.eLb + (size_t)n * Vq;
    for (int i8 = tid; i8 < Vq / 8; i8 += 256) {
        const bf16x8 e = *(const bf16x8*)(er + i8 * 8);
        float4 o0, o1;
        o0.x = (float)e[0] * scale; o0.y = (float)e[1] * scale;
        o0.z = (float)e[2] * scale; o0.w = (float)e[3] * scale;
        o1.x = (float)e[4] * scale; o1.y = (float)e[5] * scale;
        o1.z = (float)e[6] * scale; o1.w = (float)e[7] * scale;
        ((float4*)s_chunk)[i8 * 2]     = o0;
        ((float4*)s_chunk)[i8 * 2 + 1] = o1;
    }
    __syncthreads();
    {
        const int idx = p.story[b * Tq + tid];
        atomicAdd(&s_chunk[idx], (1.f - swv) * prob_f[(size_t)n * Tq + tid]);
    }
    __syncthreads();
    float* orow = p.out + ((size_t)n * Lq + step) * Vq;
    for (int i4 = tid; i4 < Vq / 4; i4 += 256)
        ((float4*)orow)[i4] = ((const float4*)s_chunk)[i4];
}

// ---------------------------------------------------------------------------
// The persistent cooperative kernel: all phases, grid.sync between.
// 480 blocks x 256 threads; 76.3 KB LDS -> 2 blocks/CU (512 capacity).
// ---------------------------------------------------------------------------
__global__ __launch_bounds__(256, 2) void mega(MegaP p)
{
    cg::grid_group grid = cg::this_grid();
    const int bid = blockIdx.x;
    const int tid = threadIdx.x;
    const int gtid = bid * 256 + tid;
    const int GT = GRID * 256;
    const int wave = tid >> 6, lane = tid & 63;

    __shared__ float s_chunk[Vq];          // 72000 B
    __shared__ float s_h[Hq], s_c[Hq];
    __shared__ float s_p[Tq];
    __shared__ float s_red[8];

    // P0: packs + conversions
    phase0_body(p, gtid, GT);
    grid.sync();

    // P1: gi_all (380 units) + gh for step 0 (152 units)
    for (int u = bid; u < NGI + NGT; u += GRID) {
        if (u < NGI) gi_unit(p, u, wave, lane);
        else         gh_unit(p, u - NGI, wave, lane);
    }
    grid.sync();

    // attn(0)
    attn_row(p, bid, 0, p.prob0, p.swp0, s_h, s_c, s_p, s_red);
    grid.sync();

    // decode loop
    for (int s = 0; s < Lq; ++s) {
        const int nu = NVU + ((s + 1 < Lq) ? NGT : 0);
        for (int u = bid; u < nu; u += GRID) {
            if (u < NVU) vocab_unit(p, u, wave, lane);
            else         gh_unit(p, u - NVU, wave, lane);
        }
        grid.sync();

        const float* pf = (s & 1) ? p.prob1 : p.prob0;
        const float* sf = (s & 1) ? p.swp1 : p.swp0;
        final_row(p, bid, s, pf, sf, s_chunk, s_red);
        if (s + 1 < Lq) {
            __syncthreads();
            float* pa = ((s + 1) & 1) ? p.prob1 : p.prob0;
            float* sa = ((s + 1) & 1) ? p.swp1 : p.swp0;
            attn_row(p, bid, s + 1, pa, sa, s_h, s_c, s_p, s_red);
        }
        grid.sync();
    }
}

// ---------------------------------------------------------------------------
// Fallback kernels (same phases as separate dispatches) in case the
// cooperative launch is rejected under graph capture.
// ---------------------------------------------------------------------------
__global__ __launch_bounds__(256, 2) void k_fb_p0(MegaP p)
{
    phase0_body(p, blockIdx.x * 256 + threadIdx.x, gridDim.x * 256);
}
__global__ __launch_bounds__(256, 2) void k_fb_p1(MegaP p)
{
    const int wave = threadIdx.x >> 6, lane = threadIdx.x & 63;
    for (int u = blockIdx.x; u < NGI + NGT; u += gridDim.x) {
        if (u < NGI) gi_unit(p, u, wave, lane);
        else         gh_unit(p, u - NGI, wave, lane);
    }
}
__global__ __launch_bounds__(256, 2) void k_fb_attn0(MegaP p)
{
    __shared__ float s_h[Hq], s_c[Hq], s_p[Tq], s_red[8];
    attn_row(p, blockIdx.x, 0, p.prob0, p.swp0, s_h, s_c, s_p, s_red);
}
__global__ __launch_bounds__(256, 2) void k_fb_vocab(MegaP p, const int nu)
{
    const int wave = threadIdx.x >> 6, lane = threadIdx.x & 63;
    for (int u = blockIdx.x; u < nu; u += gridDim.x) {
        if (u < NVU) vocab_unit(p, u, wave, lane);
        else         gh_unit(p, u - NVU, wave, lane);
    }
}
__global__ __launch_bounds__(256, 2) void k_fb_finattn(MegaP p, const int s,
    const int do_attn, const float* pf, const float* sf, float* pa, float* sa)
{
    __shared__ float s_chunk[Vq];
    __shared__ float s_h[Hq], s_c[Hq], s_p[Tq], s_red[8];
    final_row(p, blockIdx.x, s, pf, sf, s_chunk, s_red);
    if (do_attn) {
        __syncthreads();
        attn_row(p, blockIdx.x, s + 1, pa, sa, s_h, s_c, s_p, s_red);
    }
}

// ---------------------------------------------------------------------------
extern "C" void kernel_launch(void* const* d_in, const int* in_sizes, int n_in,
                              void* d_out, int out_size, void* d_ws, size_t ws_size,
                              hipStream_t stream)
{
    MegaP p;
    p.ehid    = (const float*)d_in[0];
    p.enc     = (const float*)d_in[1];
    p.emb     = (const float*)d_in[2];
    p.w_ih    = (const float*)d_in[3];
    p.w_hh    = (const float*)d_in[4];
    p.b_ih    = (const float*)d_in[5];
    p.b_hh    = (const float*)d_in[6];
    p.w_ratio = (const float*)d_in[7];
    p.b_ratio = (const float*)d_in[8];
    p.w_gate  = (const float*)d_in[9];
    p.b_gate  = (const float*)d_in[10];
    p.slot_emb= (const float*)d_in[11];
    p.lens    = (const int*)d_in[12];
    p.story   = (const int*)d_in[13];
    p.tgt     = (const int*)d_in[14];
    p.dom     = (const int*)d_in[15];
    p.slo     = (const int*)d_in[16];

    p.out = (float*)d_out;
    p.out_gates = p.out + (size_t)NSq * Bq * Lq * Vq;

    char* w = (char*)d_ws;
    size_t off = 0;
    auto alloc = [&](size_t bytes) -> void* {
        void* q = (void*)(w + off);
        off += (bytes + 255) & ~(size_t)255;
        return q;
    };
    p.xbp    = (bf16*)alloc((size_t)Lq * Nq * Hq * 2);
    p.xlin   = (bf16*)alloc((size_t)Lq * Nq * Hq * 2);
    p.hbp    = (bf16*)alloc((size_t)Nq * Hq * 2);
    p.h      = (float*)alloc((size_t)Nq * Hq * 4);
    p.gi_all = (float*)alloc((size_t)Lq * Nq * H3q * 4);
    p.gh     = (float*)alloc((size_t)Nq * H3q * 4);
    p.prob0  = (float*)alloc((size_t)Nq * Tq * 4);
    p.prob1  = (float*)alloc((size_t)Nq * Tq * 4);
    p.swp0   = (float*)alloc((size_t)Nq * 4);
    p.swp1   = (float*)alloc((size_t)Nq * 4);
    p.partial= (float*)alloc((size_t)Nq * NPB2 * 4);
    p.eLb    = (bf16*)alloc((size_t)Nq * Vq * 2);
    p.embp   = (bf16*)alloc((size_t)NGV * NKT * 64 * 8 * 2);
    p.wihp   = (bf16*)alloc((size_t)NGW * NKT * 64 * 8 * 2);
    p.whhp   = (bf16*)alloc((size_t)NGW * NKT * 64 * 8 * 2);
    p.encb   = (bf16*)alloc((size_t)Bq * Tq * Hq * 2);

    void* args[] = { (void*)&p };
    hipError_t err = hipLaunchCooperativeKernel(
        (const void*)mega, dim3(GRID), dim3(256), args, 0, stream);

    if (err != hipSuccess) {
        (void)hipGetLastError();  // clear error state; replay phases as dispatches
        k_fb_p0<<<dim3(GRID), dim3(256), 0, stream>>>(p);
        k_fb_p1<<<dim3(GRID), dim3(256), 0, stream>>>(p);
        k_fb_attn0<<<dim3(GRID), dim3(256), 0, stream>>>(p);
        for (int s = 0; s < Lq; ++s) {
            const int nu = NVU + ((s + 1 < Lq) ? NGT : 0);
            k_fb_vocab<<<dim3(nu), dim3(256), 0, stream>>>(p, nu);
            const float* pf = (s & 1) ? p.prob1 : p.prob0;
            const float* sf = (s & 1) ? p.swp1 : p.swp0;
            float* pa = ((s + 1) & 1) ? p.prob1 : p.prob0;
            float* sa = ((s + 1) & 1) ? p.swp1 : p.swp0;
            k_fb_finattn<<<dim3(Nq), dim3(256), 0, stream>>>(
                p, s, (s + 1 < Lq) ? 1 : 0, pf, sf, pa, sa);
        }
    }
}

// Round 6
// 1202.968 us; speedup vs baseline: 2.9048x; 2.9048x over previous
//
#include <hip/hip_runtime.h>
#include <hip/hip_bf16.h>

#define Bq 16
#define Tq 256
#define Vq 18000
#define NSq 30
#define Lq 10
#define Gq 3
#define Hq 400
#define Nq (NSq * Bq)      // 480
#define H3q (3 * Hq)       // 1200
#define NKT 25             // K tiles (400/16)
#define NGV 564            // embp col groups (32 cols; 18048 padded)
#define NGW 38             // weight col groups (1216 padded)
#define NGH 15             // row groups (480 rows)
#define CHq 9000           // final LDS chunk (2 chunks cover V)
#define NPB 288            // partial stride (282 used)
#define NPB_USED 282       // vocab 64-col blocks
#define NGT 152            // gh units (38 ct x 4 gsets)
#define NGI 380            // gi units (38 ct x 10 steps)

typedef __bf16 bf16;
typedef __bf16 bf16x4 __attribute__((ext_vector_type(4)));
typedef __bf16 bf16x8 __attribute__((ext_vector_type(8)));
typedef float floatx16 __attribute__((ext_vector_type(16)));

// ---------------------------------------------------------------------------
// Pack one MFMA fragment (8 bf16) from row-major f32 [nrows][400].
// frag i = ((g*25+kt)*64+lane): src(row=g*32+(lane&31), k=kt*16+(lane>>5)*8+j)
// ---------------------------------------------------------------------------
__device__ __forceinline__ void packf_one(const float* __restrict__ src,
    bf16* __restrict__ dst, const int i, const int nrows)
{
    const int lane = i & 63;
    const int kt = (i >> 6) % NKT;
    const int g = i / (NKT * 64);
    int row = g * 32 + (lane & 31);
    if (row >= nrows) row = nrows - 1;
    const int k0 = kt * 16 + (lane >> 5) * 8;
    const float* s = src + (size_t)row * Hq + k0;
    const float4 a = *(const float4*)s;
    const float4 c = *(const float4*)(s + 4);
    bf16x8 o;
    o[0] = (bf16)a.x; o[1] = (bf16)a.y; o[2] = (bf16)a.z; o[3] = (bf16)a.w;
    o[4] = (bf16)c.x; o[5] = (bf16)c.y; o[6] = (bf16)c.z; o[7] = (bf16)c.w;
    *(bf16x8*)(dst + (size_t)i * 8) = o;
}

// ---------------------------------------------------------------------------
// P0: ALL one-time packs/conversions in one dispatch (mutually independent).
// ---------------------------------------------------------------------------
__global__ __launch_bounds__(256) void k_p0(
    const float* __restrict__ emb, const float* __restrict__ w_ih,
    const float* __restrict__ w_hh, const float* __restrict__ enc,
    const float* __restrict__ slot_emb, const int* __restrict__ dom,
    const int* __restrict__ slo, const int* __restrict__ tgt,
    const float* __restrict__ ehid,
    bf16* __restrict__ embp, bf16* __restrict__ wihp, bf16* __restrict__ whhp,
    bf16* __restrict__ encb, bf16* __restrict__ xbp, bf16* __restrict__ xlin,
    float* __restrict__ h, bf16* __restrict__ hbp)
{
    const int gtid = blockIdx.x * 256 + threadIdx.x;
    const int GT = gridDim.x * 256;

    for (int i = gtid; i < NGV * NKT * 64; i += GT)
        packf_one(emb, embp, i, Vq);
    for (int i = gtid; i < NGW * NKT * 64; i += GT) {
        packf_one(w_ih, wihp, i, H3q);
        packf_one(w_hh, whhp, i, H3q);
    }
    for (int i = gtid; i < (Bq * Tq * Hq) / 4; i += GT) {
        const float4 v = ((const float4*)enc)[i];
        bf16x4 o;
        o[0] = (bf16)v.x; o[1] = (bf16)v.y; o[2] = (bf16)v.z; o[3] = (bf16)v.w;
        ((bf16x4*)encb)[i] = o;
    }
    for (int i = gtid; i < Lq * NGH * NKT * 64; i += GT) {
        const int lane = i & 63;
        const int kt = (i >> 6) % NKT;
        const int gg = i / (NKT * 64);
        const int g = gg % NGH;
        const int s = gg / NGH;
        const int n = g * 32 + (lane & 31);
        const int slot = n >> 4, b = n & (Bq - 1);
        const int k0 = kt * 16 + (lane >> 5) * 8;
        float v[8];
        if (s == 0) {
            const float* p1 = slot_emb + (size_t)dom[slot] * Hq + k0;
            const float* p2 = slot_emb + (size_t)slo[slot] * Hq + k0;
            #pragma unroll
            for (int j = 0; j < 8; ++j) v[j] = p1[j] + p2[j];
        } else {
            const int tv = tgt[(b * NSq + slot) * Lq + (s - 1)];
            const float* q = emb + (size_t)tv * Hq + k0;
            #pragma unroll
            for (int j = 0; j < 8; ++j) v[j] = q[j];
        }
        bf16x8 o;
        #pragma unroll
        for (int j = 0; j < 8; ++j) o[j] = (bf16)v[j];
        *(bf16x8*)(xbp + (size_t)i * 8) = o;
        *(bf16x8*)(xlin + ((size_t)s * Nq + n) * Hq + k0) = o;
    }
    for (int i = gtid; i < NGH * NKT * 64; i += GT) {
        const int lane = i & 63;
        const int kt = (i >> 6) % NKT;
        const int g = i / (NKT * 64);
        const int n = g * 32 + (lane & 31);
        const int b = n & (Bq - 1);
        const int k0 = kt * 16 + (lane >> 5) * 8;
        const float* s = ehid + (size_t)b * Hq + k0;
        bf16x8 o;
        #pragma unroll
        for (int j = 0; j < 8; ++j) {
            const float v = s[j];
            h[(size_t)n * Hq + k0 + j] = v;
            o[j] = (bf16)v;
        }
        *(bf16x8*)(hbp + (size_t)i * 8) = o;
    }
}

// ---------------------------------------------------------------------------
// gh unit (wave-level): gh = h_prev @ W_hh^T for (ct, g).
// ---------------------------------------------------------------------------
__device__ __forceinline__ void gh_unit(const bf16* __restrict__ hbp,
    const bf16* __restrict__ whhp, float* __restrict__ gh, const int v,
    const int wave, const int lane)
{
    const int ct = v % NGW;
    const int g = (v / NGW) * 4 + wave;
    if (g >= NGH) return;
    floatx16 acc;
    #pragma unroll
    for (int r = 0; r < 16; ++r) acc[r] = 0.f;
    for (int kt = 0; kt < NKT; ++kt) {
        const bf16x8 a = *(const bf16x8*)(hbp + ((size_t)(g * NKT + kt) * 64 + lane) * 8);
        const bf16x8 w = *(const bf16x8*)(whhp + ((size_t)(ct * NKT + kt) * 64 + lane) * 8);
        acc = __builtin_amdgcn_mfma_f32_32x32x16_bf16(a, w, acc, 0, 0, 0);
    }
    const int j = ct * 32 + (lane & 31);
    if (j >= H3q) return;
    const int rbase = g * 32 + 4 * (lane >> 5);
    #pragma unroll
    for (int r = 0; r < 16; ++r) {
        const int rr = rbase + (r & 3) + 8 * (r >> 2);
        gh[(size_t)rr * H3q + j] = acc[r];
    }
}

// ---------------------------------------------------------------------------
// P1: gi_all (380 units, block-wide) + gh for step 0 (152 units). 532 blocks.
// ---------------------------------------------------------------------------
__global__ __launch_bounds__(256) void k_p1(
    const bf16* __restrict__ xbp, const bf16* __restrict__ wihp,
    const bf16* __restrict__ hbp, const bf16* __restrict__ whhp,
    float* __restrict__ gi_all, float* __restrict__ gh)
{
    const int wave = threadIdx.x >> 6, lane = threadIdx.x & 63;
    const int u = blockIdx.x;
    if (u >= NGI) {
        gh_unit(hbp, whhp, gh, u - NGI, wave, lane);
        return;
    }
    const int ct = u % NGW;
    const int s = u / NGW;
    floatx16 acc[4];
    #pragma unroll
    for (int i = 0; i < 4; ++i)
        #pragma unroll
        for (int r = 0; r < 16; ++r) acc[i][r] = 0.f;
    for (int kt = 0; kt < NKT; ++kt) {
        const bf16x8 w = *(const bf16x8*)(wihp + ((size_t)(ct * NKT + kt) * 64 + lane) * 8);
        #pragma unroll
        for (int i = 0; i < 4; ++i) {
            const int g = wave + 4 * i;
            if (g < NGH) {
                const bf16x8 a = *(const bf16x8*)(xbp +
                    ((size_t)((s * NGH + g) * NKT + kt) * 64 + lane) * 8);
                acc[i] = __builtin_amdgcn_mfma_f32_32x32x16_bf16(a, w, acc[i], 0, 0, 0);
            }
        }
    }
    const int j = ct * 32 + (lane & 31);
    if (j >= H3q) return;
    #pragma unroll
    for (int i = 0; i < 4; ++i) {
        const int g = wave + 4 * i;
        if (g < NGH) {
            const int rbase = g * 32 + 4 * (lane >> 5);
            #pragma unroll
            for (int r = 0; r < 16; ++r) {
                const int rr = rbase + (r & 3) + 8 * (r >> 2);
                gi_all[((size_t)(s * Nq + rr)) * H3q + j] = acc[i][r];
            }
        }
    }
}

// ---------------------------------------------------------------------------
// attn row (round-3 proven body): GRU + scores + softmax + context + switch.
// smem pieces passed in: s_h[400], s_c[400], s_p[256], s_red[8].
// ---------------------------------------------------------------------------
__device__ void attn_row(const int n, const int step,
    const float* __restrict__ gi_all, const float* __restrict__ gh,
    const float* __restrict__ b_ih, const float* __restrict__ b_hh,
    float* __restrict__ h, bf16* __restrict__ hbp,
    const bf16* __restrict__ xlin, const bf16* __restrict__ encb,
    const int* __restrict__ lens, const float* __restrict__ w_ratio,
    const float* __restrict__ b_ratio, const float* __restrict__ w_gate,
    const float* __restrict__ b_gate, float* __restrict__ prob_a,
    float* __restrict__ swp_a, float* __restrict__ out_gates,
    float* s_h, float* s_c, float* s_p, float* s_red)
{
    const int b = n & (Bq - 1);
    const int tid = threadIdx.x;

    const float* gin = gi_all + ((size_t)step * Nq + n) * H3q;
    const float* ghn = gh + (size_t)n * H3q;
    for (int k = tid; k < Hq; k += 256) {
        float ir = gin[k]          + b_ih[k];
        float hr = ghn[k]          + b_hh[k];
        float iz = gin[Hq + k]     + b_ih[Hq + k];
        float hz = ghn[Hq + k]     + b_hh[Hq + k];
        float in_ = gin[2*Hq + k]  + b_ih[2*Hq + k];
        float hn_ = ghn[2*Hq + k]  + b_hh[2*Hq + k];
        float r = 1.f / (1.f + __expf(-(ir + hr)));
        float z = 1.f / (1.f + __expf(-(iz + hz)));
        float nn = tanhf(in_ + r * hn_);
        float hp = h[(size_t)n * Hq + k];
        float hv = (1.f - z) * nn + z * hp;
        s_h[k] = hv;
        h[(size_t)n * Hq + k] = hv;
        hbp[((size_t)(((n >> 5) * NKT + (k >> 4)) * 64
                      + ((k >> 3) & 1) * 32 + (n & 31))) * 8 + (k & 7)] = (bf16)hv;
    }
    __syncthreads();

    // scores: thread t over T=256 (independent, ILP-friendly)
    const int t = tid;
    const bf16* erow = encb + (size_t)(b * Tq + t) * Hq;
    float sc = 0.f;
    #pragma unroll 5
    for (int kc = 0; kc < Hq / 8; ++kc) {
        const bf16x8 e = *(const bf16x8*)(erow + kc * 8);
        #pragma unroll
        for (int j = 0; j < 8; ++j) sc += s_h[kc * 8 + j] * (float)e[j];
    }
    const int len = lens[b];
    float score = (t < len) ? sc : -1e9f;

    float mx = score;
    for (int off = 32; off > 0; off >>= 1) mx = fmaxf(mx, __shfl_xor(mx, off, 64));
    if ((tid & 63) == 0) s_red[tid >> 6] = mx;
    __syncthreads();
    mx = fmaxf(fmaxf(s_red[0], s_red[1]), fmaxf(s_red[2], s_red[3]));
    float ev = __expf(score - mx);
    float sm = ev;
    for (int off = 32; off > 0; off >>= 1) sm += __shfl_xor(sm, off, 64);
    __syncthreads();
    if ((tid & 63) == 0) s_red[tid >> 6] = sm;
    __syncthreads();
    sm = s_red[0] + s_red[1] + s_red[2] + s_red[3];
    const float pv = ev / sm;
    s_p[t] = pv;
    prob_a[(size_t)n * Tq + t] = pv;
    __syncthreads();

    // context[k] = sum_t p[t] * enc[b][t][k]  (lanes coalesced in k)
    for (int k = tid; k < Hq; k += 256) {
        float c = 0.f;
        const bf16* ecol = encb + (size_t)b * Tq * Hq + k;
        for (int tt = 0; tt < Tq; ++tt) c += s_p[tt] * (float)ecol[(size_t)tt * Hq];
        s_c[k] = c;
    }
    __syncthreads();

    const bf16* xr = xlin + ((size_t)step * Nq + n) * Hq;
    float part2 = 0.f;
    for (int k = tid; k < Hq; k += 256) {
        part2 += w_ratio[k]        * s_h[k]
               + w_ratio[Hq + k]   * s_c[k]
               + w_ratio[2*Hq + k] * (float)xr[k];
    }
    for (int off = 32; off > 0; off >>= 1) part2 += __shfl_xor(part2, off, 64);
    __syncthreads();
    if ((tid & 63) == 0) s_red[tid >> 6] = part2;
    __syncthreads();
    if (tid == 0) {
        const float tot = s_red[0] + s_red[1] + s_red[2] + s_red[3] + b_ratio[0];
        swp_a[n] = 1.f / (1.f + __expf(-tot));
    }

    if (step == 0) {
        for (int gg = 0; gg < Gq; ++gg) {
            float pg = 0.f;
            for (int k = tid; k < Hq; k += 256)
                pg += w_gate[gg * Hq + k] * s_c[k];
            for (int off = 32; off > 0; off >>= 1) pg += __shfl_xor(pg, off, 64);
            __syncthreads();
            if ((tid & 63) == 0) s_red[tid >> 6] = pg;
            __syncthreads();
            if (tid == 0)
                out_gates[n * Gq + gg] =
                    s_red[0] + s_red[1] + s_red[2] + s_red[3] + b_gate[gg];
        }
    }
}

// ---------------------------------------------------------------------------
// attn(0) standalone (computes gates too).
// ---------------------------------------------------------------------------
__global__ __launch_bounds__(256) void k_attn0(
    const float* __restrict__ gi_all, const float* __restrict__ gh,
    const float* __restrict__ b_ih, const float* __restrict__ b_hh,
    float* __restrict__ h, bf16* __restrict__ hbp,
    const bf16* __restrict__ xlin, const bf16* __restrict__ encb,
    const int* __restrict__ lens, const float* __restrict__ w_ratio,
    const float* __restrict__ b_ratio, const float* __restrict__ w_gate,
    const float* __restrict__ b_gate, float* __restrict__ prob0,
    float* __restrict__ swp0, float* __restrict__ out_gates)
{
    __shared__ float smem[2 * Hq + Tq];
    __shared__ float s_red[8];
    attn_row(blockIdx.x, 0, gi_all, gh, b_ih, b_hh, h, hbp, xlin, encb, lens,
             w_ratio, b_ratio, w_gate, b_gate, prob0, swp0, out_gates,
             smem, smem + Hq, smem + 2 * Hq, s_red);
}

// ---------------------------------------------------------------------------
// A: vocab GEMM (exp -> bf16 eLb + per-block partial sums) + gh(s+1).
// blocks <282: 64-col vocab tile; blocks >=282: gh units.
// ---------------------------------------------------------------------------
__global__ __launch_bounds__(256, 2) void k_A(
    const bf16* __restrict__ hbp, const bf16* __restrict__ embp,
    const bf16* __restrict__ whhp, bf16* __restrict__ eLb,
    float* __restrict__ partial, float* __restrict__ gh)
{
    const int wave = threadIdx.x >> 6, lane = threadIdx.x & 63;

    if (blockIdx.x >= NPB_USED) {
        gh_unit(hbp, whhp, gh, blockIdx.x - NPB_USED, wave, lane);
        return;
    }

    const int ct2 = blockIdx.x;
    floatx16 acc0[4], acc1[4];
    #pragma unroll
    for (int i = 0; i < 4; ++i)
        #pragma unroll
        for (int r = 0; r < 16; ++r) { acc0[i][r] = 0.f; acc1[i][r] = 0.f; }

    for (int kt = 0; kt < NKT; ++kt) {
        const bf16x8 w0 = *(const bf16x8*)(embp +
            ((size_t)((2 * ct2) * NKT + kt) * 64 + lane) * 8);
        const bf16x8 w1 = *(const bf16x8*)(embp +
            ((size_t)((2 * ct2 + 1) * NKT + kt) * 64 + lane) * 8);
        #pragma unroll
        for (int i = 0; i < 4; ++i) {
            const int g = wave + 4 * i;
            if (g < NGH) {
                const bf16x8 a = *(const bf16x8*)(hbp +
                    ((size_t)(g * NKT + kt) * 64 + lane) * 8);
                acc0[i] = __builtin_amdgcn_mfma_f32_32x32x16_bf16(a, w0, acc0[i], 0, 0, 0);
                acc1[i] = __builtin_amdgcn_mfma_f32_32x32x16_bf16(a, w1, acc1[i], 0, 0, 0);
            }
        }
    }

    const int mcol = lane & 31, half = lane >> 5;
    const int j0 = ct2 * 64 + mcol, j1 = j0 + 32;
    #pragma unroll
    for (int i = 0; i < 4; ++i) {
        const int g = wave + 4 * i;       // wave-uniform -> shfl below is safe
        if (g >= NGH) continue;
        const int rbase = g * 32 + 4 * half;
        #pragma unroll
        for (int r = 0; r < 16; ++r) {
            const int rr = rbase + (r & 3) + 8 * (r >> 2);
            const float e0 = (j0 < Vq) ? __expf(acc0[i][r]) : 0.f;
            const float e1 = (j1 < Vq) ? __expf(acc1[i][r]) : 0.f;
            if (j0 < Vq) eLb[(size_t)rr * Vq + j0] = (bf16)e0;
            if (j1 < Vq) eLb[(size_t)rr * Vq + j1] = (bf16)e1;
            float v = e0 + e1;
            v += __shfl_xor(v, 16, 64);
            v += __shfl_xor(v, 8, 64);
            v += __shfl_xor(v, 4, 64);
            v += __shfl_xor(v, 2, 64);
            v += __shfl_xor(v, 1, 64);
            if (mcol == 0) partial[(size_t)rr * NPB + ct2] = v;
        }
    }
}

// ---------------------------------------------------------------------------
// B: blocks [0,480) = final(step_f) with LDS-chunk scatter (round-3 proven);
//    blocks [480,960) = attn(step_f+1).  LDS overlaid (36 KB chunk).
// ---------------------------------------------------------------------------
__global__ __launch_bounds__(256) void k_B(
    const int step_f,
    const float* __restrict__ gi_all, const float* __restrict__ gh,
    const float* __restrict__ b_ih, const float* __restrict__ b_hh,
    float* __restrict__ h, bf16* __restrict__ hbp,
    const bf16* __restrict__ xlin, const bf16* __restrict__ encb,
    const int* __restrict__ lens, const float* __restrict__ w_ratio,
    const float* __restrict__ b_ratio, const float* __restrict__ w_gate,
    const float* __restrict__ b_gate, float* __restrict__ prob_a,
    float* __restrict__ swp_a, float* __restrict__ out_gates,
    const bf16* __restrict__ eLb, const float* __restrict__ prob_f,
    const float* __restrict__ swp_f, const float* __restrict__ partial,
    const int* __restrict__ story, float* __restrict__ out)
{
    __shared__ __align__(16) float smem[CHq];   // 36 KB, overlaid
    __shared__ float s_red[8];
    const int tid = threadIdx.x;

    if ((int)blockIdx.x >= Nq) {
        attn_row(blockIdx.x - Nq, step_f + 1, gi_all, gh, b_ih, b_hh, h, hbp,
                 xlin, encb, lens, w_ratio, b_ratio, w_gate, b_gate,
                 prob_a, swp_a, out_gates,
                 smem, smem + Hq, smem + 2 * Hq, s_red);
        return;
    }

    // ---------------- final(step_f) ----------------
    const int n = blockIdx.x;
    const int b = n & (Bq - 1);

    float ps = partial[(size_t)n * NPB + tid];
    if (tid < NPB_USED - 256) ps += partial[(size_t)n * NPB + 256 + tid];
    #pragma unroll
    for (int off = 32; off > 0; off >>= 1) ps += __shfl_xor(ps, off, 64);
    if ((tid & 63) == 0) s_red[tid >> 6] = ps;
    __syncthreads();
    const float rs = s_red[0] + s_red[1] + s_red[2] + s_red[3];
    const float swv = swp_f[n];
    const float scale = swv / rs;

    const bf16* er = eLb + (size_t)n * Vq;
    float* orow = out + ((size_t)n * Lq + step_f) * Vq;

    #pragma unroll
    for (int c = 0; c < 2; ++c) {
        const int c0 = c * CHq;
        for (int i8 = tid; i8 < CHq / 8; i8 += 256) {
            const bf16x8 e = *(const bf16x8*)(er + c0 + i8 * 8);
            float4 o0, o1;
            o0.x = (float)e[0] * scale; o0.y = (float)e[1] * scale;
            o0.z = (float)e[2] * scale; o0.w = (float)e[3] * scale;
            o1.x = (float)e[4] * scale; o1.y = (float)e[5] * scale;
            o1.z = (float)e[6] * scale; o1.w = (float)e[7] * scale;
            ((float4*)smem)[i8 * 2]     = o0;
            ((float4*)smem)[i8 * 2 + 1] = o1;
        }
        __syncthreads();
        {
            const int idx = story[b * Tq + tid];
            if (idx >= c0 && idx < c0 + CHq)
                atomicAdd(&smem[idx - c0], (1.f - swv) * prob_f[(size_t)n * Tq + tid]);
        }
        __syncthreads();
        for (int i4 = tid; i4 < CHq / 4; i4 += 256)
            ((float4*)(orow + c0))[i4] = ((const float4*)smem)[i4];
        if (c == 0) __syncthreads();
    }
}

// ---------------------------------------------------------------------------
extern "C" void kernel_launch(void* const* d_in, const int* in_sizes, int n_in,
                              void* d_out, int out_size, void* d_ws, size_t ws_size,
                              hipStream_t stream)
{
    const float* ehid    = (const float*)d_in[0];
    const float* enc     = (const float*)d_in[1];
    const float* emb     = (const float*)d_in[2];
    const float* w_ih    = (const float*)d_in[3];
    const float* w_hh    = (const float*)d_in[4];
    const float* b_ih    = (const float*)d_in[5];
    const float* b_hh    = (const float*)d_in[6];
    const float* w_ratio = (const float*)d_in[7];
    const float* b_ratio = (const float*)d_in[8];
    const float* w_gate  = (const float*)d_in[9];
    const float* b_gate  = (const float*)d_in[10];
    const float* slot_emb= (const float*)d_in[11];
    const int*  lens     = (const int*)d_in[12];
    const int*  story    = (const int*)d_in[13];
    const int*  tgt      = (const int*)d_in[14];
    const int*  dom      = (const int*)d_in[15];
    const int*  slo      = (const int*)d_in[16];

    float* out = (float*)d_out;
    float* out_gates = out + (size_t)NSq * Bq * Lq * Vq;

    char* w = (char*)d_ws;
    size_t off = 0;
    auto alloc = [&](size_t bytes) -> void* {
        void* q = (void*)(w + off);
        off += (bytes + 255) & ~(size_t)255;
        return q;
    };
    bf16*  xbp    = (bf16*)alloc((size_t)Lq * Nq * Hq * 2);
    bf16*  xlin   = (bf16*)alloc((size_t)Lq * Nq * Hq * 2);
    bf16*  hbp    = (bf16*)alloc((size_t)Nq * Hq * 2);
    float* h      = (float*)alloc((size_t)Nq * Hq * 4);
    float* gi_all = (float*)alloc((size_t)Lq * Nq * H3q * 4);
    float* gh     = (float*)alloc((size_t)Nq * H3q * 4);
    float* prob0  = (float*)alloc((size_t)Nq * Tq * 4);
    float* prob1  = (float*)alloc((size_t)Nq * Tq * 4);
    float* swp0   = (float*)alloc((size_t)Nq * 4);
    float* swp1   = (float*)alloc((size_t)Nq * 4);
    float* partial= (float*)alloc((size_t)Nq * NPB * 4);
    bf16*  eLb    = (bf16*)alloc((size_t)Nq * Vq * 2);
    bf16*  embp   = (bf16*)alloc((size_t)NGV * NKT * 64 * 8 * 2);
    bf16*  wihp   = (bf16*)alloc((size_t)NGW * NKT * 64 * 8 * 2);
    bf16*  whhp   = (bf16*)alloc((size_t)NGW * NKT * 64 * 8 * 2);
    bf16*  encb   = (bf16*)alloc((size_t)Bq * Tq * Hq * 2);

    // ---- prolog: 2 dispatches + attn(0) ----
    k_p0<<<dim3(2048), dim3(256), 0, stream>>>(
        emb, w_ih, w_hh, enc, slot_emb, dom, slo, tgt, ehid,
        embp, wihp, whhp, encb, xbp, xlin, h, hbp);
    k_p1<<<dim3(NGI + NGT), dim3(256), 0, stream>>>(
        xbp, wihp, hbp, whhp, gi_all, gh);
    k_attn0<<<dim3(Nq), dim3(256), 0, stream>>>(
        gi_all, gh, b_ih, b_hh, h, hbp, xlin, encb, lens,
        w_ratio, b_ratio, w_gate, b_gate, prob0, swp0, out_gates);

    // ---- decode loop: 2 dispatches/step ----
    for (int s = 0; s < Lq; ++s) {
        const int nbA = NPB_USED + ((s + 1 < Lq) ? NGT : 0);
        k_A<<<dim3(nbA), dim3(256), 0, stream>>>(
            hbp, embp, whhp, eLb, partial, gh);

        const int nbB = Nq + ((s + 1 < Lq) ? Nq : 0);
        float* pa = ((s + 1) & 1) ? prob1 : prob0;
        float* sa = ((s + 1) & 1) ? swp1 : swp0;
        const float* pf = (s & 1) ? prob1 : prob0;
        const float* sf = (s & 1) ? swp1 : swp0;
        k_B<<<dim3(nbB), dim3(256), 0, stream>>>(
            s, gi_all, gh, b_ih, b_hh, h, hbp, xlin, encb, lens,
            w_ratio, b_ratio, w_gate, b_gate, pa, sa, out_gates,
            eLb, pf, sf, partial, story, out);
    }
}